// Round 2
// baseline (14276.242 us; speedup 1.0000x reference)
//
#include <hip/hip_runtime.h>
#include <hip/hip_fp16.h>

// LSTM: B=32, T=4096, D=256, H=256, gates=1024 (i,g,f,o), HORIZON=24
// k_scan v2: 32 blocks x 512 thr. Thread t: kq=t&3 (K-quarter, 32 h-pairs),
//   cq=t>>2 -> 8 gate cols. Weights: 24 pair-rows in VGPRs (192 regs),
//   5 streamed from L2/step (anti-LICM via opaque z), 3 in LDS (pitch 1032).
//   K-partials combined with DPP quad_perm (in-register, no LDS).
//   h state in LDS as padded f16-pair quarters (stride 36 words, bank-disjoint).

#define T_STEPS 4096
#define BATCH 32
#define RROWS 24
#define SROWS 5
#define LROWS 3
#define WLPITCH 1032

typedef short short8 __attribute__((ext_vector_type(8)));
typedef float f32x4 __attribute__((ext_vector_type(4)));
typedef _Float16 half2_t __attribute__((ext_vector_type(2)));

__device__ inline unsigned short f32_to_bf16(float f) {
  unsigned int u = __builtin_bit_cast(unsigned int, f);
  u = u + 0x7fffu + ((u >> 16) & 1u);   // RNE
  return (unsigned short)(u >> 16);
}

__device__ inline float fdot2f(unsigned int w, unsigned int h, float acc) {
#if __has_builtin(__builtin_amdgcn_fdot2)
  return __builtin_amdgcn_fdot2(__builtin_bit_cast(half2_t, w),
                                __builtin_bit_cast(half2_t, h), acc, false);
#else
  half2_t a = __builtin_bit_cast(half2_t, w);
  half2_t b = __builtin_bit_cast(half2_t, h);
  acc += (float)a.x * (float)b.x;
  acc += (float)a.y * (float)b.y;
  return acc;
#endif
}

// ---------------- prep: x f32 -> bf16 ----------------
__global__ void k_prep_x(const float4* __restrict__ x, unsigned short* __restrict__ xbf, int n4) {
  int i = blockIdx.x * blockDim.x + threadIdx.x;
  if (i >= n4) return;
  float4 v = x[i];
  ushort4 o;
  o.x = f32_to_bf16(v.x); o.y = f32_to_bf16(v.y);
  o.z = f32_to_bf16(v.z); o.w = f32_to_bf16(v.w);
  ((ushort4*)xbf)[i] = o;
}

// ---------------- prep: weights ----------------
// WxT[n][k] = bf16(W_lstm[k][n]) for k<256
// Whp[p][c] = pack(f16(W_lstm[256+2p][c]), f16(W_lstm[257+2p][c]))  p in [0,128)
__global__ void k_prep_w(const float* __restrict__ W, unsigned short* __restrict__ WxT,
                         unsigned int* __restrict__ Whp) {
  int i = blockIdx.x * blockDim.x + threadIdx.x;
  if (i < 256 * 1024) {
    int n = i >> 8, k = i & 255;
    WxT[i] = f32_to_bf16(W[k * 1024 + n]);
  } else {
    int j = i - 256 * 1024;   // j in [0, 131072)
    int p = j >> 10, c = j & 1023;
    _Float16 lo = (_Float16)W[(256 + 2 * p) * 1024 + c];
    _Float16 hi = (_Float16)W[(257 + 2 * p) * 1024 + c];
    Whp[j] = (unsigned int)__builtin_bit_cast(unsigned short, lo) |
             ((unsigned int)__builtin_bit_cast(unsigned short, hi) << 16);
  }
}

// ---------------- xproj: gates_x = x @ Wx + b (+1 on f-gate) ----------------
__global__ __launch_bounds__(256) void k_xproj(const unsigned short* __restrict__ A,
                                               const unsigned short* __restrict__ BT,
                                               const float* __restrict__ bias,
                                               __half* __restrict__ G) {
  int bm = blockIdx.x * 64;
  int bn = blockIdx.y * 64;
  int lane = threadIdx.x & 63, wave = threadIdx.x >> 6;
  int wm = (wave & 1) * 32, wn = (wave >> 1) * 32;
  int q = lane >> 4, l16 = lane & 15;

  f32x4 acc[2][2] = {};
  const unsigned short* Ab = A + (size_t)(bm + wm + l16) * 256 + q * 8;
  const unsigned short* Bb = BT + (size_t)(bn + wn + l16) * 256 + q * 8;

#pragma unroll
  for (int kk = 0; kk < 8; ++kk) {
    short8 a0 = *(const short8*)(Ab + kk * 32);
    short8 a1 = *(const short8*)(Ab + 16 * 256 + kk * 32);
    short8 b0 = *(const short8*)(Bb + kk * 32);
    short8 b1 = *(const short8*)(Bb + 16 * 256 + kk * 32);
    acc[0][0] = __builtin_amdgcn_mfma_f32_16x16x32_bf16(a0, b0, acc[0][0], 0, 0, 0);
    acc[0][1] = __builtin_amdgcn_mfma_f32_16x16x32_bf16(a0, b1, acc[0][1], 0, 0, 0);
    acc[1][0] = __builtin_amdgcn_mfma_f32_16x16x32_bf16(a1, b0, acc[1][0], 0, 0, 0);
    acc[1][1] = __builtin_amdgcn_mfma_f32_16x16x32_bf16(a1, b1, acc[1][1], 0, 0, 0);
  }

#pragma unroll
  for (int nt = 0; nt < 2; ++nt) {
    int col = bn + wn + nt * 16 + l16;
    float bv = bias[col] + ((col >= 512 && col < 768) ? 1.0f : 0.0f);
#pragma unroll
    for (int mt = 0; mt < 2; ++mt) {
#pragma unroll
      for (int r = 0; r < 4; ++r) {
        int row = bm + wm + mt * 16 + q * 4 + r;
        G[(size_t)row * 1024 + col] = __float2half_rn(acc[mt][nt][r] + bv);
      }
    }
  }
}

// ---------------- recurrent scan v2 ----------------
__global__ __launch_bounds__(512)
__attribute__((amdgpu_waves_per_eu(2, 2)))
void k_scan(const unsigned int* __restrict__ Whp, const __half* __restrict__ G,
            float* __restrict__ hfin) {
  __shared__ __align__(16) unsigned int WL[12 * WLPITCH];  // 49.5 KB, rows: kq*3+r
  __shared__ __align__(16) float gates[1024];              // 4 KB
  __shared__ __align__(16) unsigned int h2[4 * 36];        // padded h quarters

  const int t = threadIdx.x;
  const int b = blockIdx.x;
  const int kq = t & 3;
  const int cq = t >> 2;          // 0..127
  const int c0 = cq * 8;          // base gate col
  const int z = (int)(blockIdx.x >> 20);   // always 0; opaque -> defeats LICM

  // stage LDS weight rows: WL[kq2*3+r][c] = Whp[32*kq2 + 29 + r][c]
  for (int i = t; i < 12 * 1024; i += 512) {
    int rr = i >> 10, c = i & 1023;
    int kq2 = rr / 3, r2 = rr - kq2 * 3;
    WL[rr * WLPITCH + c] = Whp[(size_t)(32 * kq2 + RROWS + SROWS + r2) * 1024 + c];
  }

  // register-resident weights: pair-rows [32kq, 32kq+24), 8 cols
  unsigned int w[RROWS][8];
#pragma unroll
  for (int r = 0; r < RROWS; ++r) {
    const uint4* p = (const uint4*)(Whp + (size_t)(32 * kq + r) * 1024 + c0);
    uint4 a = p[0], bb = p[1];
    w[r][0] = a.x; w[r][1] = a.y; w[r][2] = a.z; w[r][3] = a.w;
    w[r][4] = bb.x; w[r][5] = bb.y; w[r][6] = bb.z; w[r][7] = bb.w;
  }

  if (t < 144) h2[t] = 0u;   // h0 = 0 (incl. pads)
  float c_state = 0.0f;

  const unsigned short* gp = (const unsigned short*)(G + (size_t)b * T_STEPS * 1024) + (t & 255);
  unsigned short gc_i = 0, gc_g = 0, gc_f = 0, gc_o = 0;
  if (t < 256) { gc_i = gp[0]; gc_g = gp[256]; gc_f = gp[512]; gc_o = gp[768]; }
  __syncthreads();

  const unsigned int* hq = h2 + kq * 36;
  const unsigned int* sbase = Whp + (size_t)(32 * kq + RROWS) * 1024 + c0;
  const unsigned int* wlb = WL + (kq * 3) * WLPITCH + c0;

  for (int step = 0; step < T_STEPS; ++step) {
    // prefetch next step's gates_x (consumed ~1000 cy later)
    unsigned short gn_i = 0, gn_g = 0, gn_f = 0, gn_o = 0;
    if (t < 256 && step + 1 < T_STEPS) {
      const unsigned short* q = gp + (size_t)(step + 1) * 1024;
      gn_i = q[0]; gn_g = q[256]; gn_f = q[512]; gn_o = q[768];
    }

    float acc[8] = {0.f, 0.f, 0.f, 0.f, 0.f, 0.f, 0.f, 0.f};

    // phase 1: register rows (h pairs from LDS, b64, bank-disjoint per quarter)
#pragma unroll
    for (int rr = 0; rr < RROWS; rr += 2) {
      uint2 hh = *(const uint2*)(hq + rr);
#pragma unroll
      for (int c = 0; c < 8; ++c) acc[c] = fdot2f(w[rr][c], hh.x, acc[c]);
#pragma unroll
      for (int c = 0; c < 8; ++c) acc[c] = fdot2f(w[rr + 1][c], hh.y, acc[c]);
    }
    // phase 2: streamed rows (L2-hot, re-read each step)
    {
      const unsigned int* sp = sbase + z * step;
#pragma unroll
      for (int s = 0; s < SROWS; ++s) {
        uint4 a = *(const uint4*)(sp + s * 1024);
        uint4 bb = *(const uint4*)(sp + s * 1024 + 4);
        unsigned int hp = hq[RROWS + s];
        acc[0] = fdot2f(a.x, hp, acc[0]);  acc[1] = fdot2f(a.y, hp, acc[1]);
        acc[2] = fdot2f(a.z, hp, acc[2]);  acc[3] = fdot2f(a.w, hp, acc[3]);
        acc[4] = fdot2f(bb.x, hp, acc[4]); acc[5] = fdot2f(bb.y, hp, acc[5]);
        acc[6] = fdot2f(bb.z, hp, acc[6]); acc[7] = fdot2f(bb.w, hp, acc[7]);
      }
    }
    // phase 3: LDS rows
    {
      const unsigned int* wp = wlb + z * step;
#pragma unroll
      for (int r = 0; r < LROWS; ++r) {
        uint4 a = *(const uint4*)(wp + r * WLPITCH);
        uint4 bb = *(const uint4*)(wp + r * WLPITCH + 4);
        unsigned int hp = hq[RROWS + SROWS + r];
        acc[0] = fdot2f(a.x, hp, acc[0]);  acc[1] = fdot2f(a.y, hp, acc[1]);
        acc[2] = fdot2f(a.z, hp, acc[2]);  acc[3] = fdot2f(a.w, hp, acc[3]);
        acc[4] = fdot2f(bb.x, hp, acc[4]); acc[5] = fdot2f(bb.y, hp, acc[5]);
        acc[6] = fdot2f(bb.z, hp, acc[6]); acc[7] = fdot2f(bb.w, hp, acc[7]);
      }
    }

    // quad reduction over kq via DPP (all 4 lanes end with full sums)
#pragma unroll
    for (int c = 0; c < 8; ++c) {
      float v = acc[c];
      int m1 = __builtin_amdgcn_update_dpp(0, __builtin_bit_cast(int, v), 0xB1, 0xF, 0xF, true); // quad_perm(1,0,3,2)
      v += __builtin_bit_cast(float, m1);
      int m2 = __builtin_amdgcn_update_dpp(0, __builtin_bit_cast(int, v), 0x4E, 0xF, 0xF, true); // quad_perm(2,3,0,1)
      v += __builtin_bit_cast(float, m2);
      acc[c] = v;
    }
    if (kq == 0) {
      *(f32x4*)&gates[c0]     = f32x4{acc[0], acc[1], acc[2], acc[3]};
      *(f32x4*)&gates[c0 + 4] = f32x4{acc[4], acc[5], acc[6], acc[7]};
    }
    __syncthreads();

    if (t < 256) {
      int j = t;
      float gi = gates[j]       + __half2float(__builtin_bit_cast(__half, gc_i));
      float gg = gates[256 + j] + __half2float(__builtin_bit_cast(__half, gc_g));
      float gf = gates[512 + j] + __half2float(__builtin_bit_cast(__half, gc_f));
      float go = gates[768 + j] + __half2float(__builtin_bit_cast(__half, gc_o));
      float si = 1.0f / (1.0f + __expf(-gi));
      float sf = 1.0f / (1.0f + __expf(-gf));
      float so = 1.0f / (1.0f + __expf(-go));
      float eg = __expf(2.0f * gg);
      float tg = 1.0f - 2.0f / (eg + 1.0f);
      c_state = sf * c_state + si * tg;
      float ec = __expf(2.0f * c_state);
      float tc = 1.0f - 2.0f / (ec + 1.0f);
      float h = so * tc;
      int p = j >> 1, q2 = p >> 5, lr = p & 31;
      ((__half*)h2)[(q2 * 36 + lr) * 2 + (j & 1)] = __float2half_rn(h);
      if (step == T_STEPS - 1) hfin[b * 256 + j] = h;
    }
    gc_i = gn_i; gc_g = gn_g; gc_f = gn_f; gc_o = gn_o;
    __syncthreads();
  }
}

// ---------------- head: out = (h@Wfc+bfc)@Wout+bout ----------------
__global__ void k_head(const float* __restrict__ hfin, const float* __restrict__ Wfc,
                       const float* __restrict__ bfc, const float* __restrict__ Wout,
                       const float* __restrict__ bout, float* __restrict__ out) {
  __shared__ float hs[256];
  __shared__ float fcs[256];
  int b = blockIdx.x, j = threadIdx.x;
  hs[j] = hfin[b * 256 + j];
  __syncthreads();
  float acc = bfc[j];
#pragma unroll 8
  for (int k = 0; k < 256; ++k) acc += hs[k] * Wfc[k * 256 + j];
  fcs[j] = acc;
  __syncthreads();
  if (j < 24) {
    float a2 = bout[j];
#pragma unroll 8
    for (int k = 0; k < 256; ++k) a2 += fcs[k] * Wout[k * 24 + j];
    out[b * 24 + j] = a2;
  }
}

extern "C" void kernel_launch(void* const* d_in, const int* in_sizes, int n_in,
                              void* d_out, int out_size, void* d_ws, size_t ws_size,
                              hipStream_t stream) {
  const float* x    = (const float*)d_in[0];
  const float* Wl   = (const float*)d_in[1];
  const float* bl   = (const float*)d_in[2];
  const float* Wfc  = (const float*)d_in[3];
  const float* bfc  = (const float*)d_in[4];
  const float* Wout = (const float*)d_in[5];
  const float* bout = (const float*)d_in[6];
  float* out = (float*)d_out;

  char* ws = (char*)d_ws;
  unsigned short* xbf = (unsigned short*)ws;                    //  67108864  x as bf16
  unsigned short* WxT = (unsigned short*)(ws + 67108864);       //    524288  Wx^T bf16 [1024][256]
  unsigned int*   Whp = (unsigned int*)(ws + 67633152);         //    524288  Wh f16 pairs [128][1024]
  __half*         G   = (__half*)(ws + 68157440);               // 268435456  gates_x f16 [B][T][1024]
  float*          hfin= (float*)(ws + 336592896);               //     32768  final h f32

  k_prep_x<<<32768, 256, 0, stream>>>((const float4*)x, xbf, 8388608);
  k_prep_w<<<1536, 256, 0, stream>>>(Wl, WxT, Whp);
  dim3 gx(2048, 16, 1);
  k_xproj<<<gx, 256, 0, stream>>>(xbf, WxT, bl, G);
  k_scan<<<32, 512, 0, stream>>>(Whp, G, hfin);
  k_head<<<32, 256, 0, stream>>>(hfin, Wfc, bfc, Wout, bout, out);
}

// Round 3
// 9513.724 us; speedup vs baseline: 1.5006x; 1.5006x over previous
//
#include <hip/hip_runtime.h>
#include <hip/hip_fp16.h>

// LSTM: B=32, T=4096, D=256, H=256, gates=1024 (i,g,f,o), HORIZON=24
// k_scan v3: 32 blocks x 512 thr. Thread t: kq=t&3 (K-quarter: h-pairs 32kq..32kq+31),
//   cq=t>>2 -> owns cols {2cq,2cq+1} x {i,g,f,o}. 24 pair-rows/quarter in NAMED uint4
//   VGPRs (no arrays -> no scratch), 8 pair-rows/quarter in LDS (quarter stride 8200
//   words == 8 mod 32 -> only 2-way bank aliasing, free). DPP quad-reduce over kq,
//   activation in-register on kq=0/2 lanes, double-buffered h -> ONE barrier/step.

#define T_STEPS 4096
#define RROWS 24
#define QSTRIDE 8200   // LDS words per quarter block (8 rows * 1024 + 8 pad)
#define HBUFW 144      // h-pair buffer: 4 quarters * 36 words (stride 36 = bank-disjoint)

typedef short short8 __attribute__((ext_vector_type(8)));
typedef float f32x4 __attribute__((ext_vector_type(4)));
typedef _Float16 half2_t __attribute__((ext_vector_type(2)));

__device__ inline unsigned short f32_to_bf16(float f) {
  unsigned int u = __builtin_bit_cast(unsigned int, f);
  u = u + 0x7fffu + ((u >> 16) & 1u);   // RNE
  return (unsigned short)(u >> 16);
}

__device__ inline float fdot2f(unsigned int w, unsigned int h, float acc) {
  return __builtin_amdgcn_fdot2(__builtin_bit_cast(half2_t, w),
                                __builtin_bit_cast(half2_t, h), acc, false);
}

// ---------------- prep: x f32 -> bf16 ----------------
__global__ void k_prep_x(const float4* __restrict__ x, unsigned short* __restrict__ xbf, int n4) {
  int i = blockIdx.x * blockDim.x + threadIdx.x;
  if (i >= n4) return;
  float4 v = x[i];
  ushort4 o;
  o.x = f32_to_bf16(v.x); o.y = f32_to_bf16(v.y);
  o.z = f32_to_bf16(v.z); o.w = f32_to_bf16(v.w);
  ((ushort4*)xbf)[i] = o;
}

// ---------------- prep: weights ----------------
__global__ void k_prep_w(const float* __restrict__ W, unsigned short* __restrict__ WxT,
                         unsigned int* __restrict__ Whp) {
  int i = blockIdx.x * blockDim.x + threadIdx.x;
  if (i < 256 * 1024) {
    int n = i >> 8, k = i & 255;
    WxT[i] = f32_to_bf16(W[k * 1024 + n]);
  } else {
    int j = i - 256 * 1024;
    int p = j >> 10, c = j & 1023;
    _Float16 lo = (_Float16)W[(256 + 2 * p) * 1024 + c];
    _Float16 hi = (_Float16)W[(257 + 2 * p) * 1024 + c];
    Whp[j] = (unsigned int)__builtin_bit_cast(unsigned short, lo) |
             ((unsigned int)__builtin_bit_cast(unsigned short, hi) << 16);
  }
}

// ---------------- xproj: gates_x = x @ Wx + b (+1 on f-gate) ----------------
__global__ __launch_bounds__(256) void k_xproj(const unsigned short* __restrict__ A,
                                               const unsigned short* __restrict__ BT,
                                               const float* __restrict__ bias,
                                               __half* __restrict__ G) {
  int bm = blockIdx.x * 64;
  int bn = blockIdx.y * 64;
  int lane = threadIdx.x & 63, wave = threadIdx.x >> 6;
  int wm = (wave & 1) * 32, wn = (wave >> 1) * 32;
  int q = lane >> 4, l16 = lane & 15;

  f32x4 acc[2][2] = {};
  const unsigned short* Ab = A + (size_t)(bm + wm + l16) * 256 + q * 8;
  const unsigned short* Bb = BT + (size_t)(bn + wn + l16) * 256 + q * 8;

#pragma unroll
  for (int kk = 0; kk < 8; ++kk) {
    short8 a0 = *(const short8*)(Ab + kk * 32);
    short8 a1 = *(const short8*)(Ab + 16 * 256 + kk * 32);
    short8 b0 = *(const short8*)(Bb + kk * 32);
    short8 b1 = *(const short8*)(Bb + 16 * 256 + kk * 32);
    acc[0][0] = __builtin_amdgcn_mfma_f32_16x16x32_bf16(a0, b0, acc[0][0], 0, 0, 0);
    acc[0][1] = __builtin_amdgcn_mfma_f32_16x16x32_bf16(a0, b1, acc[0][1], 0, 0, 0);
    acc[1][0] = __builtin_amdgcn_mfma_f32_16x16x32_bf16(a1, b0, acc[1][0], 0, 0, 0);
    acc[1][1] = __builtin_amdgcn_mfma_f32_16x16x32_bf16(a1, b1, acc[1][1], 0, 0, 0);
  }

#pragma unroll
  for (int nt = 0; nt < 2; ++nt) {
    int col = bn + wn + nt * 16 + l16;
    float bv = bias[col] + ((col >= 512 && col < 768) ? 1.0f : 0.0f);
#pragma unroll
    for (int mt = 0; mt < 2; ++mt) {
#pragma unroll
      for (int r = 0; r < 4; ++r) {
        int row = bm + wm + mt * 16 + q * 4 + r;
        G[(size_t)row * 1024 + col] = __float2half_rn(acc[mt][nt][r] + bv);
      }
    }
  }
}

// ---------------- recurrent scan v3 ----------------
// Named-register weights: 24 rows x (wa=cols i0,i1,g0,g1 ; wb=cols f0,f1,o0,o1)
#define ROWS24(M) M(0) M(1) M(2) M(3) M(4) M(5) M(6) M(7) M(8) M(9) M(10) M(11) \
                  M(12) M(13) M(14) M(15) M(16) M(17) M(18) M(19) M(20) M(21) M(22) M(23)

#define DEF_ROW(r) uint4 wa##r, wb##r;

#define LD_ROW(r) { const unsigned int* p = Whp + (size_t)(32 * kq + (r)) * 1024 + c2; \
  uint2 pi = *(const uint2*)(p);        uint2 pg = *(const uint2*)(p + 256); \
  uint2 pf = *(const uint2*)(p + 512);  uint2 po = *(const uint2*)(p + 768); \
  wa##r = uint4{pi.x, pi.y, pg.x, pg.y}; wb##r = uint4{pf.x, pf.y, po.x, po.y}; }

#define DOT_ROW(r, hv) \
  acc0 = fdot2f(wa##r.x, (hv), acc0); acc1 = fdot2f(wa##r.y, (hv), acc1); \
  acc2 = fdot2f(wa##r.z, (hv), acc2); acc3 = fdot2f(wa##r.w, (hv), acc3); \
  acc4 = fdot2f(wb##r.x, (hv), acc4); acc5 = fdot2f(wb##r.y, (hv), acc5); \
  acc6 = fdot2f(wb##r.z, (hv), acc6); acc7 = fdot2f(wb##r.w, (hv), acc7);

#define DOT_PAIR(r0, r1) { uint2 hh = *(const uint2*)(hr + (r0)); \
  DOT_ROW(r0, hh.x); DOT_ROW(r1, hh.y); }

#define LDOT(r, hv) { uint4 la = *(const uint4*)(wp + (r) * 1024); \
  uint4 lb = *(const uint4*)(wp + (r) * 1024 + 4); \
  acc0 = fdot2f(la.x, (hv), acc0); acc1 = fdot2f(la.y, (hv), acc1); \
  acc2 = fdot2f(la.z, (hv), acc2); acc3 = fdot2f(la.w, (hv), acc3); \
  acc4 = fdot2f(lb.x, (hv), acc4); acc5 = fdot2f(lb.y, (hv), acc5); \
  acc6 = fdot2f(lb.z, (hv), acc6); acc7 = fdot2f(lb.w, (hv), acc7); }

__global__ __launch_bounds__(512, 2)
__attribute__((amdgpu_waves_per_eu(2, 2)))
void k_scan(const unsigned int* __restrict__ Whp, const __half* __restrict__ G,
            float* __restrict__ hfin) {
  __shared__ __align__(16) unsigned int WL[4 * QSTRIDE];  // 131.2 KB weight tail
  __shared__ __align__(16) unsigned int h2[2 * HBUFW];    // double-buffered h pairs

  const int t = threadIdx.x;
  const int b = blockIdx.x;
  const int kq = t & 3;
  const int cq = t >> 2;                 // 0..127
  const int c2 = 2 * cq;
  const int z = (int)(blockIdx.x >> 20); // always 0; opaque -> defeats LICM

  // stage WL: word q*QSTRIDE + r*1024 + cq*8 + c  <-  Whp[32q+24+r][ (c>>1)*256 + 2cq + (c&1) ]
  for (int i = t; i < 4 * 8 * 1024; i += 512) {
    int q = i >> 13, rr = (i >> 10) & 7, k = i & 1023;
    int scq = k >> 3, sc = k & 7;
    int col = ((sc >> 1) << 8) + 2 * scq + (sc & 1);
    WL[q * QSTRIDE + rr * 1024 + k] = Whp[(size_t)(32 * q + RROWS + rr) * 1024 + col];
  }

  ROWS24(DEF_ROW)
  ROWS24(LD_ROW)

  if (t < 2 * HBUFW) h2[t] = 0u;   // zero both h buffers (incl. pads)

  // per-thread gate-x column (valid for kq 0/2 lanes): col = 2cq + (kq>>1)
  const __half* gp2 = G + (size_t)b * T_STEPS * 1024 + (c2 + (kq >> 1));
  const bool act_lane = (kq & 1) == 0;
  float gxi = 0.f, gxg = 0.f, gxf = 0.f, gxo = 0.f;
  if (act_lane) {
    gxi = __half2float(gp2[0]);   gxg = __half2float(gp2[256]);
    gxf = __half2float(gp2[512]); gxo = __half2float(gp2[768]);
  }
  float c_state = 0.0f;
  __syncthreads();

  const unsigned int* wpb = WL + kq * QSTRIDE + cq * 8;

  for (int step = 0; step < T_STEPS; ++step) {
    // prefetch next step's gate-x (consumed next iteration, ~1300 cy away)
    float ni = 0.f, ng = 0.f, nf = 0.f, no = 0.f;
    {
      int nx = step + 1 < T_STEPS ? step + 1 : T_STEPS - 1;
      if (act_lane) {
        const __half* q = gp2 + (size_t)nx * 1024;
        ni = __half2float(q[0]);   ng = __half2float(q[256]);
        nf = __half2float(q[512]); no = __half2float(q[768]);
      }
    }

    const int rd = (step & 1) * HBUFW;
    const unsigned int* hr = h2 + rd + kq * 36;   // this quarter's h pairs (read buf)

    float acc0 = 0.f, acc1 = 0.f, acc2 = 0.f, acc3 = 0.f;
    float acc4 = 0.f, acc5 = 0.f, acc6 = 0.f, acc7 = 0.f;

    // register rows 0..23
    DOT_PAIR(0, 1)   DOT_PAIR(2, 3)   DOT_PAIR(4, 5)   DOT_PAIR(6, 7)
    DOT_PAIR(8, 9)   DOT_PAIR(10, 11) DOT_PAIR(12, 13) DOT_PAIR(14, 15)
    DOT_PAIR(16, 17) DOT_PAIR(18, 19) DOT_PAIR(20, 21) DOT_PAIR(22, 23)

    // LDS rows 24..31 (weights re-read each step; z*step defeats hoisting)
    {
      const unsigned int* wp = wpb + z * step;
      uint2 hx0 = *(const uint2*)(hr + 24);
      uint2 hx1 = *(const uint2*)(hr + 26);
      uint2 hx2 = *(const uint2*)(hr + 28);
      uint2 hx3 = *(const uint2*)(hr + 30);
      LDOT(0, hx0.x) LDOT(1, hx0.y) LDOT(2, hx1.x) LDOT(3, hx1.y)
      LDOT(4, hx2.x) LDOT(5, hx2.y) LDOT(6, hx3.x) LDOT(7, hx3.y)
    }

    // quad reduction over kq via DPP
#define QRED(a) { \
    int m1 = __builtin_amdgcn_update_dpp(0, __builtin_bit_cast(int, a), 0xB1, 0xF, 0xF, true); \
    a += __builtin_bit_cast(float, m1); \
    int m2 = __builtin_amdgcn_update_dpp(0, __builtin_bit_cast(int, a), 0x4E, 0xF, 0xF, true); \
    a += __builtin_bit_cast(float, m2); }
    QRED(acc0) QRED(acc1) QRED(acc2) QRED(acc3)
    QRED(acc4) QRED(acc5) QRED(acc6) QRED(acc7)
#undef QRED

    if (act_lane) {
      const int s = kq >> 1;   // which of the 2 cols this lane handles
      float gi = (s ? acc1 : acc0) + gxi;
      float gg = (s ? acc3 : acc2) + gxg;
      float gf = (s ? acc5 : acc4) + gxf;   // +1 folded in G
      float go = (s ? acc7 : acc6) + gxo;
      float si = 1.0f / (1.0f + __expf(-gi));
      float sf = 1.0f / (1.0f + __expf(-gf));
      float so = 1.0f / (1.0f + __expf(-go));
      float eg = __expf(2.0f * gg);
      float tg = 1.0f - 2.0f / (eg + 1.0f);
      c_state = sf * c_state + si * tg;
      float ec = __expf(2.0f * c_state);
      float tc = 1.0f - 2.0f / (ec + 1.0f);
      float h = so * tc;
      // write h into the OTHER buffer: pair word (cq>>5)*36 + (cq&31), half s
      __half* hw = (__half*)(h2 + (HBUFW - rd));
      hw[(((cq >> 5) * 36) + (cq & 31)) * 2 + s] = __float2half_rn(h);
      if (step == T_STEPS - 1) hfin[b * 256 + c2 + s] = h;
    }
    gxi = ni; gxg = ng; gxf = nf; gxo = no;
    __syncthreads();
  }
}

// ---------------- head ----------------
__global__ void k_head(const float* __restrict__ hfin, const float* __restrict__ Wfc,
                       const float* __restrict__ bfc, const float* __restrict__ Wout,
                       const float* __restrict__ bout, float* __restrict__ out) {
  __shared__ float hs[256];
  __shared__ float fcs[256];
  int b = blockIdx.x, j = threadIdx.x;
  hs[j] = hfin[b * 256 + j];
  __syncthreads();
  float acc = bfc[j];
#pragma unroll 8
  for (int k = 0; k < 256; ++k) acc += hs[k] * Wfc[k * 256 + j];
  fcs[j] = acc;
  __syncthreads();
  if (j < 24) {
    float a2 = bout[j];
#pragma unroll 8
    for (int k = 0; k < 256; ++k) a2 += fcs[k] * Wout[k * 24 + j];
    out[b * 24 + j] = a2;
  }
}

extern "C" void kernel_launch(void* const* d_in, const int* in_sizes, int n_in,
                              void* d_out, int out_size, void* d_ws, size_t ws_size,
                              hipStream_t stream) {
  const float* x    = (const float*)d_in[0];
  const float* Wl   = (const float*)d_in[1];
  const float* bl   = (const float*)d_in[2];
  const float* Wfc  = (const float*)d_in[3];
  const float* bfc  = (const float*)d_in[4];
  const float* Wout = (const float*)d_in[5];
  const float* bout = (const float*)d_in[6];
  float* out = (float*)d_out;

  char* ws = (char*)d_ws;
  unsigned short* xbf = (unsigned short*)ws;                    //  67108864  x as bf16
  unsigned short* WxT = (unsigned short*)(ws + 67108864);       //    524288  Wx^T bf16
  unsigned int*   Whp = (unsigned int*)(ws + 67633152);         //    524288  Wh f16 pairs [128][1024]
  __half*         G   = (__half*)(ws + 68157440);               // 268435456  gates_x f16 [B][T][1024]
  float*          hfin= (float*)(ws + 336592896);               //     32768  final h f32

  k_prep_x<<<32768, 256, 0, stream>>>((const float4*)x, xbf, 8388608);
  k_prep_w<<<1536, 256, 0, stream>>>(Wl, WxT, Whp);
  dim3 gx(2048, 16, 1);
  k_xproj<<<gx, 256, 0, stream>>>(xbf, WxT, bl, G);
  k_scan<<<32, 512, 0, stream>>>(Whp, G, hfin);
  k_head<<<32, 256, 0, stream>>>(hfin, Wfc, bfc, Wout, bout, out);
}

// Round 4
// 9219.695 us; speedup vs baseline: 1.5485x; 1.0319x over previous
//
#include <hip/hip_runtime.h>
#include <hip/hip_fp16.h>

// LSTM: B=32, T=4096, D=256, H=256, gates=1024 (i,g,f,o), HORIZON=24
// k_scan v4: 32 blocks x 512 thr, EXACT 2 waves/EU (amdgpu_waves_per_eu(2,2), no
//   __launch_bounds__) -> 256-VGPR budget so the 24x8 named weight regs actually
//   allocate. Tail 8 pair-rows/quarter in LDS with wave-linear layout
//   TL[r][wave][half][lane][4w]: every ds_read_b128 is lane-contiguous (1KB/wave)
//   -> zero bank conflicts. DPP quad-reduce, in-register activation, 1 barrier/step.

#define T_STEPS 4096
#define RROWS 24
#define HBUFW 144      // h-pair buffer: 4 quarters * 36 words (bank-disjoint)

typedef short short8 __attribute__((ext_vector_type(8)));
typedef float f32x4 __attribute__((ext_vector_type(4)));
typedef _Float16 half2_t __attribute__((ext_vector_type(2)));

__device__ inline unsigned short f32_to_bf16(float f) {
  unsigned int u = __builtin_bit_cast(unsigned int, f);
  u = u + 0x7fffu + ((u >> 16) & 1u);   // RNE
  return (unsigned short)(u >> 16);
}

__device__ inline float fdot2f(unsigned int w, unsigned int h, float acc) {
  return __builtin_amdgcn_fdot2(__builtin_bit_cast(half2_t, w),
                                __builtin_bit_cast(half2_t, h), acc, false);
}

// ---------------- prep: x f32 -> bf16 ----------------
__global__ void k_prep_x(const float4* __restrict__ x, unsigned short* __restrict__ xbf, int n4) {
  int i = blockIdx.x * blockDim.x + threadIdx.x;
  if (i >= n4) return;
  float4 v = x[i];
  ushort4 o;
  o.x = f32_to_bf16(v.x); o.y = f32_to_bf16(v.y);
  o.z = f32_to_bf16(v.z); o.w = f32_to_bf16(v.w);
  ((ushort4*)xbf)[i] = o;
}

// ---------------- prep: weights ----------------
__global__ void k_prep_w(const float* __restrict__ W, unsigned short* __restrict__ WxT,
                         unsigned int* __restrict__ Whp) {
  int i = blockIdx.x * blockDim.x + threadIdx.x;
  if (i < 256 * 1024) {
    int n = i >> 8, k = i & 255;
    WxT[i] = f32_to_bf16(W[k * 1024 + n]);
  } else {
    int j = i - 256 * 1024;
    int p = j >> 10, c = j & 1023;
    _Float16 lo = (_Float16)W[(256 + 2 * p) * 1024 + c];
    _Float16 hi = (_Float16)W[(257 + 2 * p) * 1024 + c];
    Whp[j] = (unsigned int)__builtin_bit_cast(unsigned short, lo) |
             ((unsigned int)__builtin_bit_cast(unsigned short, hi) << 16);
  }
}

// ---------------- xproj: gates_x = x @ Wx + b (+1 on f-gate) ----------------
__global__ __launch_bounds__(256) void k_xproj(const unsigned short* __restrict__ A,
                                               const unsigned short* __restrict__ BT,
                                               const float* __restrict__ bias,
                                               __half* __restrict__ G) {
  int bm = blockIdx.x * 64;
  int bn = blockIdx.y * 64;
  int lane = threadIdx.x & 63, wave = threadIdx.x >> 6;
  int wm = (wave & 1) * 32, wn = (wave >> 1) * 32;
  int q = lane >> 4, l16 = lane & 15;

  f32x4 acc[2][2] = {};
  const unsigned short* Ab = A + (size_t)(bm + wm + l16) * 256 + q * 8;
  const unsigned short* Bb = BT + (size_t)(bn + wn + l16) * 256 + q * 8;

#pragma unroll
  for (int kk = 0; kk < 8; ++kk) {
    short8 a0 = *(const short8*)(Ab + kk * 32);
    short8 a1 = *(const short8*)(Ab + 16 * 256 + kk * 32);
    short8 b0 = *(const short8*)(Bb + kk * 32);
    short8 b1 = *(const short8*)(Bb + 16 * 256 + kk * 32);
    acc[0][0] = __builtin_amdgcn_mfma_f32_16x16x32_bf16(a0, b0, acc[0][0], 0, 0, 0);
    acc[0][1] = __builtin_amdgcn_mfma_f32_16x16x32_bf16(a0, b1, acc[0][1], 0, 0, 0);
    acc[1][0] = __builtin_amdgcn_mfma_f32_16x16x32_bf16(a1, b0, acc[1][0], 0, 0, 0);
    acc[1][1] = __builtin_amdgcn_mfma_f32_16x16x32_bf16(a1, b1, acc[1][1], 0, 0, 0);
  }

#pragma unroll
  for (int nt = 0; nt < 2; ++nt) {
    int col = bn + wn + nt * 16 + l16;
    float bv = bias[col] + ((col >= 512 && col < 768) ? 1.0f : 0.0f);
#pragma unroll
    for (int mt = 0; mt < 2; ++mt) {
#pragma unroll
      for (int r = 0; r < 4; ++r) {
        int row = bm + wm + mt * 16 + q * 4 + r;
        G[(size_t)row * 1024 + col] = __float2half_rn(acc[mt][nt][r] + bv);
      }
    }
  }
}

// ---------------- recurrent scan v4 ----------------
#define ROWS24(M) M(0) M(1) M(2) M(3) M(4) M(5) M(6) M(7) M(8) M(9) M(10) M(11) \
                  M(12) M(13) M(14) M(15) M(16) M(17) M(18) M(19) M(20) M(21) M(22) M(23)

#define DEF_ROW(r) uint4 wa##r, wb##r;

#define LD_ROW(r) { const unsigned int* p = Whp + (size_t)(32 * kq + (r)) * 1024 + c2; \
  uint2 pi = *(const uint2*)(p);        uint2 pg = *(const uint2*)(p + 256); \
  uint2 pf = *(const uint2*)(p + 512);  uint2 po = *(const uint2*)(p + 768); \
  wa##r = uint4{pi.x, pi.y, pg.x, pg.y}; wb##r = uint4{pf.x, pf.y, po.x, po.y}; }

#define DOT_ROW(r, hv) \
  acc0 = fdot2f(wa##r.x, (hv), acc0); acc1 = fdot2f(wa##r.y, (hv), acc1); \
  acc2 = fdot2f(wa##r.z, (hv), acc2); acc3 = fdot2f(wa##r.w, (hv), acc3); \
  acc4 = fdot2f(wb##r.x, (hv), acc4); acc5 = fdot2f(wb##r.y, (hv), acc5); \
  acc6 = fdot2f(wb##r.z, (hv), acc6); acc7 = fdot2f(wb##r.w, (hv), acc7);

#define DOT_PAIR(r0, r1) { uint2 hh = *(const uint2*)(hr + (r0)); \
  DOT_ROW(r0, hh.x); DOT_ROW(r1, hh.y); }

// tail row r: la at wp + r*4096, lb at +256 (wave-linear, conflict-free b128)
#define LDOT(r, hv) { uint4 la = *(const uint4*)(wp + (r) * 4096); \
  uint4 lb = *(const uint4*)(wp + (r) * 4096 + 256); \
  acc0 = fdot2f(la.x, (hv), acc0); acc1 = fdot2f(la.y, (hv), acc1); \
  acc2 = fdot2f(la.z, (hv), acc2); acc3 = fdot2f(la.w, (hv), acc3); \
  acc4 = fdot2f(lb.x, (hv), acc4); acc5 = fdot2f(lb.y, (hv), acc5); \
  acc6 = fdot2f(lb.z, (hv), acc6); acc7 = fdot2f(lb.w, (hv), acc7); }

__global__
__attribute__((amdgpu_flat_work_group_size(512, 512), amdgpu_waves_per_eu(2, 2)))
void k_scan(const unsigned int* __restrict__ Whp, const __half* __restrict__ G,
            float* __restrict__ hfin) {
  // WL[r][wave][half][lane][4w]: r<8, wave<8, half<2, lane<64 -> 32768 words (128 KB)
  __shared__ __align__(16) unsigned int WL[8 * 4096];
  __shared__ __align__(16) unsigned int h2[2 * HBUFW];    // double-buffered h pairs

  const int t = threadIdx.x;
  const int b = blockIdx.x;
  const int kq = t & 3;
  const int cq = t >> 2;                 // 0..127
  const int c2 = 2 * cq;
  const int wv = t >> 6, ln = t & 63;
  const int z = (int)(blockIdx.x >> 20); // always 0; opaque -> defeats LICM

  // stage WL: dest word i = r*4096 + w*512 + half*256 + l*4 + j
  //   source: thread (kq_s=l&3, cq_s=w*16+(l>>2)), c = half*4+j,
  //   col = ((c>>1)<<8) + 2*cq_s + (c&1), pair-row = 32*kq_s + 24 + r
  for (int i = t; i < 8 * 4096; i += 512) {
    int r = i >> 12, w = (i >> 9) & 7, half = (i >> 8) & 1, l = (i >> 2) & 63, j = i & 3;
    int c = half * 4 + j;
    int cq_s = w * 16 + (l >> 2);
    int col = ((c >> 1) << 8) + 2 * cq_s + (c & 1);
    WL[i] = Whp[(size_t)(32 * (l & 3) + RROWS + r) * 1024 + col];
  }

  ROWS24(DEF_ROW)
  ROWS24(LD_ROW)

  if (t < 2 * HBUFW) h2[t] = 0u;   // zero both h buffers (incl. pads)

  // per-thread gate-x column (valid for kq 0/2 lanes): col = 2cq + (kq>>1)
  const __half* gp2 = G + (size_t)b * T_STEPS * 1024 + (c2 + (kq >> 1));
  const bool act_lane = (kq & 1) == 0;
  float gxi = 0.f, gxg = 0.f, gxf = 0.f, gxo = 0.f;
  if (act_lane) {
    gxi = __half2float(gp2[0]);   gxg = __half2float(gp2[256]);
    gxf = __half2float(gp2[512]); gxo = __half2float(gp2[768]);
  }
  float c_state = 0.0f;
  __syncthreads();

  const unsigned int* wpb = WL + wv * 512 + ln * 4;

  for (int step = 0; step < T_STEPS; ++step) {
    // prefetch next step's gate-x (consumed next iteration)
    float ni = 0.f, ng = 0.f, nf = 0.f, no = 0.f;
    {
      int nx = step + 1 < T_STEPS ? step + 1 : T_STEPS - 1;
      if (act_lane) {
        const __half* q = gp2 + (size_t)nx * 1024;
        ni = __half2float(q[0]);   ng = __half2float(q[256]);
        nf = __half2float(q[512]); no = __half2float(q[768]);
      }
    }

    const int rd = (step & 1) * HBUFW;
    const unsigned int* hr = h2 + rd + kq * 36;   // this quarter's h pairs (read buf)

    float acc0 = 0.f, acc1 = 0.f, acc2 = 0.f, acc3 = 0.f;
    float acc4 = 0.f, acc5 = 0.f, acc6 = 0.f, acc7 = 0.f;

    // register rows 0..23
    DOT_PAIR(0, 1)   DOT_PAIR(2, 3)   DOT_PAIR(4, 5)   DOT_PAIR(6, 7)
    DOT_PAIR(8, 9)   DOT_PAIR(10, 11) DOT_PAIR(12, 13) DOT_PAIR(14, 15)
    DOT_PAIR(16, 17) DOT_PAIR(18, 19) DOT_PAIR(20, 21) DOT_PAIR(22, 23)

    // LDS tail rows 24..31 (wave-linear layout; z*step defeats hoisting)
    {
      const unsigned int* wp = wpb + z * step;
      uint2 hx0 = *(const uint2*)(hr + 24);
      uint2 hx1 = *(const uint2*)(hr + 26);
      uint2 hx2 = *(const uint2*)(hr + 28);
      uint2 hx3 = *(const uint2*)(hr + 30);
      LDOT(0, hx0.x) LDOT(1, hx0.y) LDOT(2, hx1.x) LDOT(3, hx1.y)
      LDOT(4, hx2.x) LDOT(5, hx2.y) LDOT(6, hx3.x) LDOT(7, hx3.y)
    }

    // quad reduction over kq via DPP
#define QRED(a) { \
    int m1 = __builtin_amdgcn_update_dpp(0, __builtin_bit_cast(int, a), 0xB1, 0xF, 0xF, true); \
    a += __builtin_bit_cast(float, m1); \
    int m2 = __builtin_amdgcn_update_dpp(0, __builtin_bit_cast(int, a), 0x4E, 0xF, 0xF, true); \
    a += __builtin_bit_cast(float, m2); }
    QRED(acc0) QRED(acc1) QRED(acc2) QRED(acc3)
    QRED(acc4) QRED(acc5) QRED(acc6) QRED(acc7)
#undef QRED

    if (act_lane) {
      const int s = kq >> 1;   // which of the 2 cols this lane handles
      float gi = (s ? acc1 : acc0) + gxi;
      float gg = (s ? acc3 : acc2) + gxg;
      float gf = (s ? acc5 : acc4) + gxf;   // +1 folded in G
      float go = (s ? acc7 : acc6) + gxo;
      float si = 1.0f / (1.0f + __expf(-gi));
      float sf = 1.0f / (1.0f + __expf(-gf));
      float so = 1.0f / (1.0f + __expf(-go));
      float eg = __expf(2.0f * gg);
      float tg = 1.0f - 2.0f / (eg + 1.0f);
      c_state = sf * c_state + si * tg;
      float ec = __expf(2.0f * c_state);
      float tc = 1.0f - 2.0f / (ec + 1.0f);
      float h = so * tc;
      __half* hw = (__half*)(h2 + (HBUFW - rd));
      hw[(((cq >> 5) * 36) + (cq & 31)) * 2 + s] = __float2half_rn(h);
      if (step == T_STEPS - 1) hfin[b * 256 + c2 + s] = h;
    }
    gxi = ni; gxg = ng; gxf = nf; gxo = no;
    __syncthreads();
  }
}

// ---------------- head ----------------
__global__ void k_head(const float* __restrict__ hfin, const float* __restrict__ Wfc,
                       const float* __restrict__ bfc, const float* __restrict__ Wout,
                       const float* __restrict__ bout, float* __restrict__ out) {
  __shared__ float hs[256];
  __shared__ float fcs[256];
  int b = blockIdx.x, j = threadIdx.x;
  hs[j] = hfin[b * 256 + j];
  __syncthreads();
  float acc = bfc[j];
#pragma unroll 8
  for (int k = 0; k < 256; ++k) acc += hs[k] * Wfc[k * 256 + j];
  fcs[j] = acc;
  __syncthreads();
  if (j < 24) {
    float a2 = bout[j];
#pragma unroll 8
    for (int k = 0; k < 256; ++k) a2 += fcs[k] * Wout[k * 24 + j];
    out[b * 24 + j] = a2;
  }
}

extern "C" void kernel_launch(void* const* d_in, const int* in_sizes, int n_in,
                              void* d_out, int out_size, void* d_ws, size_t ws_size,
                              hipStream_t stream) {
  const float* x    = (const float*)d_in[0];
  const float* Wl   = (const float*)d_in[1];
  const float* bl   = (const float*)d_in[2];
  const float* Wfc  = (const float*)d_in[3];
  const float* bfc  = (const float*)d_in[4];
  const float* Wout = (const float*)d_in[5];
  const float* bout = (const float*)d_in[6];
  float* out = (float*)d_out;

  char* ws = (char*)d_ws;
  unsigned short* xbf = (unsigned short*)ws;                    //  67108864  x as bf16
  unsigned short* WxT = (unsigned short*)(ws + 67108864);       //    524288  Wx^T bf16
  unsigned int*   Whp = (unsigned int*)(ws + 67633152);         //    524288  Wh f16 pairs [128][1024]
  __half*         G   = (__half*)(ws + 68157440);               // 268435456  gates_x f16 [B][T][1024]
  float*          hfin= (float*)(ws + 336592896);               //     32768  final h f32

  k_prep_x<<<32768, 256, 0, stream>>>((const float4*)x, xbf, 8388608);
  k_prep_w<<<1536, 256, 0, stream>>>(Wl, WxT, Whp);
  dim3 gx(2048, 16, 1);
  k_xproj<<<gx, 256, 0, stream>>>(xbf, WxT, bl, G);
  k_scan<<<32, 512, 0, stream>>>(Whp, G, hfin);
  k_head<<<32, 256, 0, stream>>>(hfin, Wfc, bfc, Wout, bout, out);
}

// Round 5
// 9218.458 us; speedup vs baseline: 1.5487x; 1.0001x over previous
//
#include <hip/hip_runtime.h>
#include <hip/hip_fp16.h>

// LSTM: B=32, T=4096, D=256, H=256, gates=1024 (i,g,f,o), HORIZON=24
// k_scan v5: v4 + OPAQUE REGISTER PIN. The 24x8 weight values are loaded then
//   passed through empty asm("+v") so their defs are asm outputs — the compiler
//   can no longer sink/reload the loads inside the loop (the v2-v4 failure mode:
//   VGPR_Count stuck at 120 while the loop re-read weights from L1 every step).
//   Budget: amdgpu_waves_per_eu(2,2) + amdgpu_num_vgpr(248) -> 232-reg live set fits.

#define T_STEPS 4096
#define RROWS 24
#define HBUFW 144      // h-pair buffer: 4 quarters * 36 words (bank-disjoint)

typedef short short8 __attribute__((ext_vector_type(8)));
typedef float f32x4 __attribute__((ext_vector_type(4)));
typedef _Float16 half2_t __attribute__((ext_vector_type(2)));
typedef unsigned int u32x2 __attribute__((ext_vector_type(2)));
typedef unsigned int u32x4 __attribute__((ext_vector_type(4)));

__device__ inline unsigned short f32_to_bf16(float f) {
  unsigned int u = __builtin_bit_cast(unsigned int, f);
  u = u + 0x7fffu + ((u >> 16) & 1u);   // RNE
  return (unsigned short)(u >> 16);
}

__device__ inline float fdot2f(unsigned int w, unsigned int h, float acc) {
  return __builtin_amdgcn_fdot2(__builtin_bit_cast(half2_t, w),
                                __builtin_bit_cast(half2_t, h), acc, false);
}

// ---------------- prep: x f32 -> bf16 ----------------
__global__ void k_prep_x(const float4* __restrict__ x, unsigned short* __restrict__ xbf, int n4) {
  int i = blockIdx.x * blockDim.x + threadIdx.x;
  if (i >= n4) return;
  float4 v = x[i];
  ushort4 o;
  o.x = f32_to_bf16(v.x); o.y = f32_to_bf16(v.y);
  o.z = f32_to_bf16(v.z); o.w = f32_to_bf16(v.w);
  ((ushort4*)xbf)[i] = o;
}

// ---------------- prep: weights ----------------
__global__ void k_prep_w(const float* __restrict__ W, unsigned short* __restrict__ WxT,
                         unsigned int* __restrict__ Whp) {
  int i = blockIdx.x * blockDim.x + threadIdx.x;
  if (i < 256 * 1024) {
    int n = i >> 8, k = i & 255;
    WxT[i] = f32_to_bf16(W[k * 1024 + n]);
  } else {
    int j = i - 256 * 1024;
    int p = j >> 10, c = j & 1023;
    _Float16 lo = (_Float16)W[(256 + 2 * p) * 1024 + c];
    _Float16 hi = (_Float16)W[(257 + 2 * p) * 1024 + c];
    Whp[j] = (unsigned int)__builtin_bit_cast(unsigned short, lo) |
             ((unsigned int)__builtin_bit_cast(unsigned short, hi) << 16);
  }
}

// ---------------- xproj: gates_x = x @ Wx + b (+1 on f-gate) ----------------
__global__ __launch_bounds__(256) void k_xproj(const unsigned short* __restrict__ A,
                                               const unsigned short* __restrict__ BT,
                                               const float* __restrict__ bias,
                                               __half* __restrict__ G) {
  int bm = blockIdx.x * 64;
  int bn = blockIdx.y * 64;
  int lane = threadIdx.x & 63, wave = threadIdx.x >> 6;
  int wm = (wave & 1) * 32, wn = (wave >> 1) * 32;
  int q = lane >> 4, l16 = lane & 15;

  f32x4 acc[2][2] = {};
  const unsigned short* Ab = A + (size_t)(bm + wm + l16) * 256 + q * 8;
  const unsigned short* Bb = BT + (size_t)(bn + wn + l16) * 256 + q * 8;

#pragma unroll
  for (int kk = 0; kk < 8; ++kk) {
    short8 a0 = *(const short8*)(Ab + kk * 32);
    short8 a1 = *(const short8*)(Ab + 16 * 256 + kk * 32);
    short8 b0 = *(const short8*)(Bb + kk * 32);
    short8 b1 = *(const short8*)(Bb + 16 * 256 + kk * 32);
    acc[0][0] = __builtin_amdgcn_mfma_f32_16x16x32_bf16(a0, b0, acc[0][0], 0, 0, 0);
    acc[0][1] = __builtin_amdgcn_mfma_f32_16x16x32_bf16(a0, b1, acc[0][1], 0, 0, 0);
    acc[1][0] = __builtin_amdgcn_mfma_f32_16x16x32_bf16(a1, b0, acc[1][0], 0, 0, 0);
    acc[1][1] = __builtin_amdgcn_mfma_f32_16x16x32_bf16(a1, b1, acc[1][1], 0, 0, 0);
  }

#pragma unroll
  for (int nt = 0; nt < 2; ++nt) {
    int col = bn + wn + nt * 16 + l16;
    float bv = bias[col] + ((col >= 512 && col < 768) ? 1.0f : 0.0f);
#pragma unroll
    for (int mt = 0; mt < 2; ++mt) {
#pragma unroll
      for (int r = 0; r < 4; ++r) {
        int row = bm + wm + mt * 16 + q * 4 + r;
        G[(size_t)row * 1024 + col] = __float2half_rn(acc[mt][nt][r] + bv);
      }
    }
  }
}

// ---------------- recurrent scan v5 ----------------
#define ROWS24(M) M(0) M(1) M(2) M(3) M(4) M(5) M(6) M(7) M(8) M(9) M(10) M(11) \
                  M(12) M(13) M(14) M(15) M(16) M(17) M(18) M(19) M(20) M(21) M(22) M(23)

#define DEF_ROW(r) u32x4 wa##r, wb##r;

#define LD_ROW(r) { const unsigned int* p = Whp + (size_t)(32 * kq + (r)) * 1024 + c2; \
  u32x2 pi = *(const u32x2*)(p);        u32x2 pg = *(const u32x2*)(p + 256); \
  u32x2 pf = *(const u32x2*)(p + 512);  u32x2 po = *(const u32x2*)(p + 768); \
  wa##r = u32x4{pi.x, pi.y, pg.x, pg.y}; wb##r = u32x4{pf.x, pf.y, po.x, po.y}; }

// opaque pin: defs become asm outputs -> cannot be sunk/reloaded from memory
#define PIN_ROW2(r0, r1) asm volatile("" : "+v"(wa##r0), "+v"(wb##r0), "+v"(wa##r1), "+v"(wb##r1));

#define DOT_ROW(r, hv) \
  acc0 = fdot2f(wa##r.x, (hv), acc0); acc1 = fdot2f(wa##r.y, (hv), acc1); \
  acc2 = fdot2f(wa##r.z, (hv), acc2); acc3 = fdot2f(wa##r.w, (hv), acc3); \
  acc4 = fdot2f(wb##r.x, (hv), acc4); acc5 = fdot2f(wb##r.y, (hv), acc5); \
  acc6 = fdot2f(wb##r.z, (hv), acc6); acc7 = fdot2f(wb##r.w, (hv), acc7);

#define DOT_PAIR(r0, r1) { u32x2 hh = *(const u32x2*)(hr + (r0)); \
  DOT_ROW(r0, hh.x); DOT_ROW(r1, hh.y); }

// tail row r: la at wp + r*4096, lb at +256 (wave-linear, conflict-free b128)
#define LDOT(r, hv) { u32x4 la = *(const u32x4*)(wp + (r) * 4096); \
  u32x4 lb = *(const u32x4*)(wp + (r) * 4096 + 256); \
  acc0 = fdot2f(la.x, (hv), acc0); acc1 = fdot2f(la.y, (hv), acc1); \
  acc2 = fdot2f(la.z, (hv), acc2); acc3 = fdot2f(la.w, (hv), acc3); \
  acc4 = fdot2f(lb.x, (hv), acc4); acc5 = fdot2f(lb.y, (hv), acc5); \
  acc6 = fdot2f(lb.z, (hv), acc6); acc7 = fdot2f(lb.w, (hv), acc7); }

__global__
__attribute__((amdgpu_flat_work_group_size(512, 512), amdgpu_waves_per_eu(2, 2),
               amdgpu_num_vgpr(248)))
void k_scan(const unsigned int* __restrict__ Whp, const __half* __restrict__ G,
            float* __restrict__ hfin) {
  // WL[r][wave][half][lane][4w]: r<8, wave<8, half<2, lane<64 -> 32768 words (128 KB)
  __shared__ __align__(16) unsigned int WL[8 * 4096];
  __shared__ __align__(16) unsigned int h2[2 * HBUFW];    // double-buffered h pairs

  const int t = threadIdx.x;
  const int b = blockIdx.x;
  const int kq = t & 3;
  const int cq = t >> 2;                 // 0..127
  const int c2 = 2 * cq;
  const int wv = t >> 6, ln = t & 63;
  const int z = (int)(blockIdx.x >> 20); // always 0; opaque -> defeats LICM

  // stage WL: dest word i = r*4096 + w*512 + half*256 + l*4 + j
  for (int i = t; i < 8 * 4096; i += 512) {
    int r = i >> 12, w = (i >> 9) & 7, half = (i >> 8) & 1, l = (i >> 2) & 63, j = i & 3;
    int c = half * 4 + j;
    int cq_s = w * 16 + (l >> 2);
    int col = ((c >> 1) << 8) + 2 * cq_s + (c & 1);
    WL[i] = Whp[(size_t)(32 * (l & 3) + RROWS + r) * 1024 + col];
  }

  ROWS24(DEF_ROW)
  ROWS24(LD_ROW)
  PIN_ROW2(0, 1)   PIN_ROW2(2, 3)   PIN_ROW2(4, 5)   PIN_ROW2(6, 7)
  PIN_ROW2(8, 9)   PIN_ROW2(10, 11) PIN_ROW2(12, 13) PIN_ROW2(14, 15)
  PIN_ROW2(16, 17) PIN_ROW2(18, 19) PIN_ROW2(20, 21) PIN_ROW2(22, 23)

  if (t < 2 * HBUFW) h2[t] = 0u;   // zero both h buffers (incl. pads)

  // per-thread gate-x column (valid for kq 0/2 lanes): col = 2cq + (kq>>1)
  const __half* gp2 = G + (size_t)b * T_STEPS * 1024 + (c2 + (kq >> 1));
  const bool act_lane = (kq & 1) == 0;
  float gxi = 0.f, gxg = 0.f, gxf = 0.f, gxo = 0.f;
  if (act_lane) {
    gxi = __half2float(gp2[0]);   gxg = __half2float(gp2[256]);
    gxf = __half2float(gp2[512]); gxo = __half2float(gp2[768]);
  }
  float c_state = 0.0f;
  __syncthreads();

  const unsigned int* wpb = WL + wv * 512 + ln * 4;

  for (int step = 0; step < T_STEPS; ++step) {
    // prefetch next step's gate-x (consumed next iteration)
    float ni = 0.f, ng = 0.f, nf = 0.f, no = 0.f;
    {
      int nx = step + 1 < T_STEPS ? step + 1 : T_STEPS - 1;
      if (act_lane) {
        const __half* q = gp2 + (size_t)nx * 1024;
        ni = __half2float(q[0]);   ng = __half2float(q[256]);
        nf = __half2float(q[512]); no = __half2float(q[768]);
      }
    }

    const int rd = (step & 1) * HBUFW;
    const unsigned int* hr = h2 + rd + kq * 36;   // this quarter's h pairs (read buf)

    float acc0 = 0.f, acc1 = 0.f, acc2 = 0.f, acc3 = 0.f;
    float acc4 = 0.f, acc5 = 0.f, acc6 = 0.f, acc7 = 0.f;

    // register rows 0..23
    DOT_PAIR(0, 1)   DOT_PAIR(2, 3)   DOT_PAIR(4, 5)   DOT_PAIR(6, 7)
    DOT_PAIR(8, 9)   DOT_PAIR(10, 11) DOT_PAIR(12, 13) DOT_PAIR(14, 15)
    DOT_PAIR(16, 17) DOT_PAIR(18, 19) DOT_PAIR(20, 21) DOT_PAIR(22, 23)

    // LDS tail rows 24..31 (wave-linear layout; z*step defeats hoisting)
    {
      const unsigned int* wp = wpb + z * step;
      u32x2 hx0 = *(const u32x2*)(hr + 24);
      u32x2 hx1 = *(const u32x2*)(hr + 26);
      u32x2 hx2 = *(const u32x2*)(hr + 28);
      u32x2 hx3 = *(const u32x2*)(hr + 30);
      LDOT(0, hx0.x) LDOT(1, hx0.y) LDOT(2, hx1.x) LDOT(3, hx1.y)
      LDOT(4, hx2.x) LDOT(5, hx2.y) LDOT(6, hx3.x) LDOT(7, hx3.y)
    }

    // quad reduction over kq via DPP
#define QRED(a) { \
    int m1 = __builtin_amdgcn_update_dpp(0, __builtin_bit_cast(int, a), 0xB1, 0xF, 0xF, true); \
    a += __builtin_bit_cast(float, m1); \
    int m2 = __builtin_amdgcn_update_dpp(0, __builtin_bit_cast(int, a), 0x4E, 0xF, 0xF, true); \
    a += __builtin_bit_cast(float, m2); }
    QRED(acc0) QRED(acc1) QRED(acc2) QRED(acc3)
    QRED(acc4) QRED(acc5) QRED(acc6) QRED(acc7)
#undef QRED

    if (act_lane) {
      const int s = kq >> 1;   // which of the 2 cols this lane handles
      float gi = (s ? acc1 : acc0) + gxi;
      float gg = (s ? acc3 : acc2) + gxg;
      float gf = (s ? acc5 : acc4) + gxf;   // +1 folded in G
      float go = (s ? acc7 : acc6) + gxo;
      float si = 1.0f / (1.0f + __expf(-gi));
      float sf = 1.0f / (1.0f + __expf(-gf));
      float so = 1.0f / (1.0f + __expf(-go));
      float eg = __expf(2.0f * gg);
      float tg = 1.0f - 2.0f / (eg + 1.0f);
      c_state = sf * c_state + si * tg;
      float ec = __expf(2.0f * c_state);
      float tc = 1.0f - 2.0f / (ec + 1.0f);
      float h = so * tc;
      __half* hw = (__half*)(h2 + (HBUFW - rd));
      hw[(((cq >> 5) * 36) + (cq & 31)) * 2 + s] = __float2half_rn(h);
      if (step == T_STEPS - 1) hfin[b * 256 + c2 + s] = h;
    }
    gxi = ni; gxg = ng; gxf = nf; gxo = no;
    __syncthreads();
  }
}

// ---------------- head ----------------
__global__ void k_head(const float* __restrict__ hfin, const float* __restrict__ Wfc,
                       const float* __restrict__ bfc, const float* __restrict__ Wout,
                       const float* __restrict__ bout, float* __restrict__ out) {
  __shared__ float hs[256];
  __shared__ float fcs[256];
  int b = blockIdx.x, j = threadIdx.x;
  hs[j] = hfin[b * 256 + j];
  __syncthreads();
  float acc = bfc[j];
#pragma unroll 8
  for (int k = 0; k < 256; ++k) acc += hs[k] * Wfc[k * 256 + j];
  fcs[j] = acc;
  __syncthreads();
  if (j < 24) {
    float a2 = bout[j];
#pragma unroll 8
    for (int k = 0; k < 256; ++k) a2 += fcs[k] * Wout[k * 24 + j];
    out[b * 24 + j] = a2;
  }
}

extern "C" void kernel_launch(void* const* d_in, const int* in_sizes, int n_in,
                              void* d_out, int out_size, void* d_ws, size_t ws_size,
                              hipStream_t stream) {
  const float* x    = (const float*)d_in[0];
  const float* Wl   = (const float*)d_in[1];
  const float* bl   = (const float*)d_in[2];
  const float* Wfc  = (const float*)d_in[3];
  const float* bfc  = (const float*)d_in[4];
  const float* Wout = (const float*)d_in[5];
  const float* bout = (const float*)d_in[6];
  float* out = (float*)d_out;

  char* ws = (char*)d_ws;
  unsigned short* xbf = (unsigned short*)ws;                    //  67108864  x as bf16
  unsigned short* WxT = (unsigned short*)(ws + 67108864);       //    524288  Wx^T bf16
  unsigned int*   Whp = (unsigned int*)(ws + 67633152);         //    524288  Wh f16 pairs [128][1024]
  __half*         G   = (__half*)(ws + 68157440);               // 268435456  gates_x f16 [B][T][1024]
  float*          hfin= (float*)(ws + 336592896);               //     32768  final h f32

  k_prep_x<<<32768, 256, 0, stream>>>((const float4*)x, xbf, 8388608);
  k_prep_w<<<1536, 256, 0, stream>>>(Wl, WxT, Whp);
  dim3 gx(2048, 16, 1);
  k_xproj<<<gx, 256, 0, stream>>>(xbf, WxT, bl, G);
  k_scan<<<32, 512, 0, stream>>>(Whp, G, hfin);
  k_head<<<32, 256, 0, stream>>>(hfin, Wfc, bfc, Wout, bout, out);
}